// Round 5
// baseline (101349.274 us; speedup 1.0000x reference)
//
#include <hip/hip_runtime.h>
#include <hip/hip_bf16.h>

#define TT 2048
#define BB 32
#define DD 256
#define HH 512
#define NWG 32      // workgroups per layer
#define UPW 16      // hidden units per workgroup

typedef unsigned long long u64;
typedef unsigned u32;
using f32x4 = __attribute__((ext_vector_type(4))) float;
using s16x8 = __attribute__((ext_vector_type(8))) short;

// Tagged h history: u64 word = [h_even | h_odd<<16 | slot_t<<32], WRITE-ONCE
// per slot per call. Valid tag => final data (stale/zero lines show wrong
// tag). Produced with sc0+sc1 write-through; consumed sc0 (L2 fast path)
// with agent-load escape. No flags, no fences, no drains on the step path.
__device__ __attribute__((aligned(16))) u64 g_h0t[TT + 1][BB][HH / 2];
__device__ __attribute__((aligned(16))) u64 g_h1t[TT + 1][BB][HH / 2];
__device__ __attribute__((aligned(16))) __hip_bfloat16 g_xb[BB][TT][DD];
__device__ __attribute__((aligned(16))) float g_h1f[BB][HH];
__device__ int g_claim[8];       // per-XCD claim counters
__device__ int g_nfull;          // XCD fill order
__device__ int g_xcdL0, g_xcdL1; // chosen XCDs (speed-only hint)

#define SLOT_B 65536   // BB * (HH/2) * 8 bytes per t-slot
#define BROW_B 2048    // (HH/2) * 8 bytes per batch row

__device__ __forceinline__ short f2bf(float f) {
    union { float f; unsigned u; } v; v.f = f;
    unsigned r = v.u + 0x7fffu + ((v.u >> 16) & 1u);  // RNE
    return (short)(r >> 16);
}
__device__ __forceinline__ float sigm(float x) { return 1.f / (1.f + __expf(-x)); }
__device__ __forceinline__ float tanh_f(float x) { return 1.f - 2.f / (__expf(2.f * x) + 1.f); }

// sc0: bypass L1, read/served by the XCD's L2. sc0+sc1 store: write-through
// to the device coherence point (updates L2 lines it passes).
__device__ __forceinline__ void ld8_sc0(u64& dst, u64 base, u32 voff) {
    asm volatile("global_load_dwordx2 %0, %1, %2 sc0" : "=&v"(dst) : "v"(voff), "s"(base));
}
__device__ __forceinline__ void st8_wt(u64 base, u32 voff, u64 val) {
    asm volatile("global_store_dwordx2 %0, %1, %2 sc0 sc1" :: "v"(voff), "v"(val), "s"(base));
}
#define VMCNT0() asm volatile("s_waitcnt vmcnt(0)")
#define SCHED_FENCE() __builtin_amdgcn_sched_barrier(0)

// ---------------------------------------------------------------------------
template <int LAYER>
__device__ void scan_layer(char* smem, int wgk,
                           const float* __restrict__ Wih, const float* __restrict__ Whh,
                           const float* __restrict__ bih, const float* __restrict__ bhh) {
    constexpr int KIN = (LAYER == 0) ? DD : HH;  // 256 / 512
    constexpr int KL  = KIN + HH;                // 768 / 1024
    constexpr int QK  = KL / 4;
    constexpr int NKQ = QK / 32;
    constexpr int ROWB = 2048;                   // LDS A row stride (bytes)

    const int tid  = threadIdx.x;
    const int wave = tid >> 6;
    const int lane = tid & 63;
    const int m    = wave & 1;
    const int q    = wave >> 1;
    const int u16i = lane & 15;
    const int hi   = lane >> 4;

    // ---- weights into registers (one-time; needs the 256-VGPR budget) -----
    s16x8 wreg[NKQ * 4];
    {
        const int unit = wgk * UPW + u16i;
#pragma unroll
        for (int ks = 0; ks < NKQ; ++ks) {
#pragma unroll
            for (int gt = 0; gt < 4; ++gt) {
                const int k = q * QK + ks * 32 + hi * 8;
                const float* src = (k < KIN)
                    ? (Wih + (size_t)(gt * HH + unit) * KIN + k)
                    : (Whh + (size_t)(gt * HH + unit) * HH + (k - KIN));
                s16x8 w;
#pragma unroll
                for (int j = 0; j < 8; ++j) w[j] = f2bf(src[j]);
                wreg[ks * 4 + gt] = w;
            }
        }
    }

    const int eb = tid >> 4;
    const int eu = tid & 15;
    const int unit_g = wgk * UPW + eu;
    float bias[4];
#pragma unroll
    for (int gt = 0; gt < 4; ++gt)
        bias[gt] = bih[gt * HH + unit_g] + bhh[gt * HH + unit_g];
    float c = 0.f;

    const int sb = tid >> 4;
    const int sk = tid & 15;

    float* gbuf = (float*)(smem + 65536);  // disjoint from A region

    const u64 bown = (u64)(uintptr_t)(LAYER == 0 ? &g_h0t[0][0][0] : &g_h1t[0][0][0]);

    for (int t = 0; t < TT; ++t) {
        // ---- [B] own-layer h[t]: batched sc0 issue (OLDEST in vmcnt order)
        u64 ow[16];
        const u32 obase = (u32)t * SLOT_B + (u32)sb * BROW_B;
        SCHED_FENCE();
#pragma unroll
        for (int w = 0; w < 16; ++w)
            ld8_sc0(ow[w], bown, obase + (u32)((sk + 16 * (w >> 2)) * 32 + (w & 3) * 8));
        SCHED_FENCE();

        // ---- [A] L1: cross-layer h0[t+1] early agent issue (younger) ------
        u64 hm[16];
        if constexpr (LAYER == 1) {
#pragma unroll
            for (int g = 0; g < 4; ++g)
#pragma unroll
                for (int j = 0; j < 4; ++j)
                    hm[g * 4 + j] = __hip_atomic_load(&g_h0t[t + 1][sb][(sk + 16 * g) * 4 + j],
                                                      __ATOMIC_RELAXED, __HIP_MEMORY_SCOPE_AGENT);
            SCHED_FENCE();
        }

        // ---- [C] L0: stage x (read-only, plain cached loads) --------------
        if constexpr (LAYER == 0) {
#pragma unroll
            for (int g = 0; g < 2; ++g) {
                const int kg = sk + 16 * g;
                s16x8 v = *(const s16x8*)&g_xb[sb][t][kg * 8];
                *(s16x8*)(smem + sb * ROWB + ((kg * 16) ^ ((sb & 7) << 4))) = v;
            }
        }

        // wait for the sc0 batch; L1 leaves the 16 younger agent loads in flight
        if constexpr (LAYER == 1) { asm volatile("s_waitcnt vmcnt(16)"); }
        else                      { VMCNT0(); }
        SCHED_FENCE();

        // ---- [D] own tag-retry: sc0 rounds w/ backoff, then agent escape --
        {
            const u32 tago = (u32)t;
            int rounds = 0;
            for (;;) {
                u32 bad = 0;
#pragma unroll
                for (int w = 0; w < 16; ++w)
                    if ((u32)(ow[w] >> 32) != tago) bad |= (1u << w);
                if (!bad) break;
                if (++rounds > 40000) break;  // wrong answer beats hang
                if (rounds <= 48) {
                    __builtin_amdgcn_s_sleep(1);
#pragma unroll
                    for (int w = 0; w < 16; ++w)
                        if (bad & (1u << w))
                            ld8_sc0(ow[w], bown, obase + (u32)((sk + 16 * (w >> 2)) * 32 + (w & 3) * 8));
                    VMCNT0();
                    SCHED_FENCE();
                } else {
                    __builtin_amdgcn_s_sleep(8);
                    const u64* op = (const u64*)(uintptr_t)(bown + obase);
#pragma unroll
                    for (int w = 0; w < 16; ++w)
                        if (bad & (1u << w))
                            ow[w] = __hip_atomic_load(op + (sk + 16 * (w >> 2)) * 4 + (w & 3),
                                                      __ATOMIC_RELAXED, __HIP_MEMORY_SCOPE_AGENT);
                }
            }
#pragma unroll
            for (int g = 0; g < 4; ++g) {
                const int kg = sk + 16 * (g + (LAYER == 0 ? 2 : 4));
                s16x8 v;
#pragma unroll
                for (int j = 0; j < 4; ++j) {
                    v[2 * j]     = (short)(u32)ow[g * 4 + j];
                    v[2 * j + 1] = (short)((u32)ow[g * 4 + j] >> 16);
                }
                *(s16x8*)(smem + sb * ROWB + ((kg * 16) ^ ((sb & 7) << 4))) = v;
            }
        }

        // ---- [E] L1: cross tag-retry (agent, backoff) + stage -------------
        if constexpr (LAYER == 1) {
            const u32 tagc = (u32)(t + 1);
            int rounds = 0;
            for (;;) {
                u32 bad = 0;
#pragma unroll
                for (int w = 0; w < 16; ++w)
                    if ((u32)(hm[w] >> 32) != tagc) bad |= (1u << w);
                if (!bad) break;
                if (++rounds > 40000) break;
                __builtin_amdgcn_s_sleep(2);
#pragma unroll
                for (int g = 0; g < 4; ++g)
#pragma unroll
                    for (int j = 0; j < 4; ++j)
                        if (bad & (1u << (g * 4 + j)))
                            hm[g * 4 + j] = __hip_atomic_load(&g_h0t[t + 1][sb][(sk + 16 * g) * 4 + j],
                                                              __ATOMIC_RELAXED, __HIP_MEMORY_SCOPE_AGENT);
            }
#pragma unroll
            for (int g = 0; g < 4; ++g) {
                const int kg = sk + 16 * g;
                s16x8 v;
#pragma unroll
                for (int j = 0; j < 4; ++j) {
                    v[2 * j]     = (short)(u32)hm[g * 4 + j];
                    v[2 * j + 1] = (short)((u32)hm[g * 4 + j] >> 16);
                }
                *(s16x8*)(smem + sb * ROWB + ((kg * 16) ^ ((sb & 7) << 4))) = v;
            }
        }

        __syncthreads();  // b2: A tile complete

        // ---- MFMA ----------------------------------------------------------
        f32x4 acc[4] = {{0,0,0,0},{0,0,0,0},{0,0,0,0},{0,0,0,0}};
        {
            const int arow = m * 16 + u16i;
            const char* abase = smem + arow * ROWB;
            const int aswz = (arow & 7) << 4;
#pragma unroll
            for (int ks = 0; ks < NKQ; ++ks) {
                const int off = (q * QK + ks * 32 + hi * 8) * 2;
                s16x8 a = *(const s16x8*)(abase + (off ^ aswz));
#pragma unroll
                for (int gt = 0; gt < 4; ++gt)
                    acc[gt] = __builtin_amdgcn_mfma_f32_16x16x32_bf16(a, wreg[ks * 4 + gt], acc[gt], 0, 0, 0);
            }
        }

        // ---- partials -> gbuf (disjoint region) ----------------------------
#pragma unroll
        for (int gt = 0; gt < 4; ++gt) {
#pragma unroll
            for (int r = 0; r < 4; ++r) {
                const int b = m * 16 + hi * 4 + r;  // C row = (lane>>4)*4 + reg
                gbuf[(q * BB + b) * 68 + gt * 16 + u16i] = acc[gt][r];
            }
        }

        __syncthreads();  // b3: partials complete

        // ---- gates, state, tagged publish (fire-and-forget) ----------------
        {
            float gv[4];
#pragma unroll
            for (int gt = 0; gt < 4; ++gt) {
                float s = bias[gt];
#pragma unroll
                for (int qq = 0; qq < 4; ++qq) s += gbuf[(qq * BB + eb) * 68 + gt * 16 + eu];
                gv[gt] = s;
            }
            const float ig = sigm(gv[0]);
            const float fg = sigm(gv[1]);
            const float gg = tanh_f(gv[2]);
            const float og = sigm(gv[3]);
            c = fg * c + ig * gg;
            const float h = og * tanh_f(c);
            const u32 hu = (u32)(unsigned short)f2bf(h);
            const u32 other = __shfl_xor(hu, 1);
            if (LAYER == 1 && t == TT - 1) g_h1f[eb][unit_g] = h;
            if ((eu & 1) == 0) {
                const u64 wv = (u64)(hu | (other << 16)) | ((u64)(u32)(t + 1) << 32);
                st8_wt(bown, (u32)(t + 1) * SLOT_B + (u32)eb * BROW_B + (u32)(unit_g / 2) * 8, wv);
            }
            SCHED_FENCE();
        }
    }
}

__global__ __launch_bounds__(512, 1) void lstm_scan(
    const float* __restrict__ Wih0, const float* __restrict__ Whh0,
    const float* __restrict__ bih0, const float* __restrict__ bhh0,
    const float* __restrict__ Wih1, const float* __restrict__ Whh1,
    const float* __restrict__ bih1, const float* __restrict__ bhh1) {
    __shared__ __attribute__((aligned(16))) char smem[65536 + 4 * BB * 68 * 4];
    __shared__ int s_layer, s_wgk;
    if (threadIdx.x == 0) {
        int xcd;
        asm volatile("s_getreg_b32 %0, hwreg(HW_REG_XCC_ID)" : "=s"(xcd));
        xcd &= 7;
        int layer = -1, wgk = 0;
        const int idx = __hip_atomic_fetch_add(&g_claim[xcd], 1, __ATOMIC_RELAXED, __HIP_MEMORY_SCOPE_AGENT);
        if (idx < NWG) {
            if (idx == NWG - 1) {
                const int slot = __hip_atomic_fetch_add(&g_nfull, 1, __ATOMIC_RELAXED, __HIP_MEMORY_SCOPE_AGENT);
                if (slot == 0)
                    __hip_atomic_store(&g_xcdL0, xcd, __ATOMIC_RELAXED, __HIP_MEMORY_SCOPE_AGENT);
                else if (slot == 1)
                    __hip_atomic_store(&g_xcdL1, xcd, __ATOMIC_RELAXED, __HIP_MEMORY_SCOPE_AGENT);
            }
            int it = 0;
            for (;;) {
                const int a = __hip_atomic_load(&g_xcdL0, __ATOMIC_RELAXED, __HIP_MEMORY_SCOPE_AGENT);
                const int b = __hip_atomic_load(&g_xcdL1, __ATOMIC_RELAXED, __HIP_MEMORY_SCOPE_AGENT);
                if (a >= 0 && b >= 0) {
                    if (xcd == a) layer = 0;
                    else if (xcd == b) layer = 1;
                    break;
                }
                if (++it > (1 << 24)) break;
            }
            wgk = idx;
        }
        s_layer = layer;
        s_wgk = wgk;
    }
    __syncthreads();
    const int layer = s_layer, wgk = s_wgk;
    if (layer < 0) return;
    if (layer == 0) scan_layer<0>(smem, wgk, Wih0, Whh0, bih0, bhh0);
    else            scan_layer<1>(smem, wgk, Wih1, Whh1, bih1, bhh1);
}

// prep: reset claim scalars; cast x->bf16; zero BOTH tagged h arrays
// (stale tags from a previous call are valid-looking -> must be cleared;
// slot 0 zero == {h=0, tag=0} which self-validates for t=0).
__global__ void prep_kernel(const float* __restrict__ x) {
    const int wg = blockIdx.x;
    const int tid = threadIdx.x;
    if (wg == 0) {
        if (tid < 8) g_claim[tid] = 0;
        if (tid == 8) { g_nfull = 0; g_xcdL0 = -1; g_xcdL1 = -1; }
    }
    if (wg >= 2) {
        const size_t i = (size_t)(wg - 2) * 256 + tid;  // one 8-float group
        const float4* xs = (const float4*)x + i * 2;
        const float4 a = xs[0], b = xs[1];
        s16x8 v;
        v[0] = f2bf(a.x); v[1] = f2bf(a.y); v[2] = f2bf(a.z); v[3] = f2bf(a.w);
        v[4] = f2bf(b.x); v[5] = f2bf(b.y); v[6] = f2bf(b.z); v[7] = f2bf(b.w);
        ((s16x8*)&g_xb[0][0][0])[i] = v;
        ulonglong2* p0 = (ulonglong2*)&g_h0t[0][0][0];
        ulonglong2* p1 = (ulonglong2*)&g_h1t[0][0][0];
        const size_t n = (size_t)(TT + 1) * BB * (HH / 2) / 2;  // 8,392,704 x 16B
        const ulonglong2 z = {0ull, 0ull};
        for (size_t k = i; k < n; k += (size_t)8192 * 256) { p0[k] = z; p1[k] = z; }
    }
}

__global__ void out_kernel(const float* __restrict__ Wout, const float* __restrict__ bout,
                           float* __restrict__ out) {
    const int b = blockIdx.x;
    const int o = threadIdx.x;
    const float4* h4 = (const float4*)&g_h1f[b][0];
    const float4* w4 = (const float4*)(Wout + (size_t)o * HH);
    float s = bout[o];
    for (int k = 0; k < HH / 4; ++k) {
        const float4 a = h4[k], w = w4[k];
        s += a.x * w.x + a.y * w.y + a.z * w.z + a.w * w.w;
    }
    out[b * 256 + o] = s;
}

extern "C" void kernel_launch(void* const* d_in, const int* in_sizes, int n_in,
                              void* d_out, int out_size, void* d_ws, size_t ws_size,
                              hipStream_t stream) {
    const float* x    = (const float*)d_in[0];
    const float* Wih0 = (const float*)d_in[1];
    const float* Whh0 = (const float*)d_in[2];
    const float* bih0 = (const float*)d_in[3];
    const float* bhh0 = (const float*)d_in[4];
    const float* Wih1 = (const float*)d_in[5];
    const float* Whh1 = (const float*)d_in[6];
    const float* bih1 = (const float*)d_in[7];
    const float* bhh1 = (const float*)d_in[8];
    const float* Wout = (const float*)d_in[9];
    const float* bout = (const float*)d_in[10];
    float* out = (float*)d_out;

    hipLaunchKernelGGL(prep_kernel, dim3(2 + 8192), dim3(256), 0, stream, x);
    hipLaunchKernelGGL(lstm_scan, dim3(256), dim3(512), 0, stream,
                       Wih0, Whh0, bih0, bhh0, Wih1, Whh1, bih1, bhh1);
    hipLaunchKernelGGL(out_kernel, dim3(BB), dim3(256), 0, stream, Wout, bout, out);
}

// Round 6
// 21162.488 us; speedup vs baseline: 4.7891x; 4.7891x over previous
//
#include <hip/hip_runtime.h>
#include <hip/hip_bf16.h>

#define TT 2048
#define BB 32
#define DD 256
#define HH 512
#define NWG 32      // workgroups per layer
#define UPW 16      // hidden units per workgroup

typedef unsigned long long u64;
typedef unsigned u32;
using f32x4 = __attribute__((ext_vector_type(4))) float;
using s16x8 = __attribute__((ext_vector_type(8))) short;

// Tagged h history: u64 word = [h_even | h_odd<<16 | slot_t<<32], write-once
// per slot per call, relaxed agent atomics only (MALL-coherent; NO sc0/sc1
// asm, NO fences, NO drains anywhere in the step loop). Valid tag => final
// data under any cache behavior. Flags are per-wave monotonic step counters
// used only to gate retry bandwidth (correctness rests on tags alone).
__device__ __attribute__((aligned(16))) u64 g_h0t[TT + 1][BB][HH / 2];
__device__ __attribute__((aligned(16))) u64 g_h1t[TT + 1][BB][HH / 2];
__device__ __attribute__((aligned(16))) __hip_bfloat16 g_xb[BB][TT][DD];
__device__ __attribute__((aligned(16))) float g_h1f[BB][HH];
__device__ int g_wf0[NWG * 8];   // per-wave monotonic counters, layer 0
__device__ int g_wf1[NWG * 8];   // layer 1

__device__ __forceinline__ short f2bf(float f) {
    union { float f; unsigned u; } v; v.f = f;
    unsigned r = v.u + 0x7fffu + ((v.u >> 16) & 1u);  // RNE
    return (short)(r >> 16);
}
__device__ __forceinline__ float sigm(float x) { return 1.f / (1.f + __expf(-x)); }
__device__ __forceinline__ float tanh_f(float x) { return 1.f - 2.f / (__expf(2.f * x) + 1.f); }

__device__ __forceinline__ u64 ald(const u64* p) {
    return __hip_atomic_load(p, __ATOMIC_RELAXED, __HIP_MEMORY_SCOPE_AGENT);
}
__device__ __forceinline__ int aldi(const int* p) {
    return __hip_atomic_load(p, __ATOMIC_RELAXED, __HIP_MEMORY_SCOPE_AGENT);
}
#define SCHED_FENCE() __builtin_amdgcn_sched_barrier(0)

// ---------------------------------------------------------------------------
template <int LAYER>
__device__ void scan_layer(char* smem, int wgk,
                           const float* __restrict__ Wih, const float* __restrict__ Whh,
                           const float* __restrict__ bih, const float* __restrict__ bhh) {
    constexpr int KIN = (LAYER == 0) ? DD : HH;  // 256 / 512
    constexpr int KL  = KIN + HH;                // 768 / 1024
    constexpr int QK  = KL / 4;
    constexpr int NKQ = QK / 32;
    constexpr int ROWB = 2048;                   // LDS A row stride (bytes)

    const int tid  = threadIdx.x;
    const int wave = tid >> 6;
    const int lane = tid & 63;
    const int m    = wave & 1;
    const int q    = wave >> 1;
    const int u16i = lane & 15;
    const int hi   = lane >> 4;

    // ---- weights into registers (one-time) --------------------------------
    s16x8 wreg[NKQ * 4];
    {
        const int unit = wgk * UPW + u16i;
#pragma unroll
        for (int ks = 0; ks < NKQ; ++ks) {
#pragma unroll
            for (int gt = 0; gt < 4; ++gt) {
                const int k = q * QK + ks * 32 + hi * 8;
                const float* src = (k < KIN)
                    ? (Wih + (size_t)(gt * HH + unit) * KIN + k)
                    : (Whh + (size_t)(gt * HH + unit) * HH + (k - KIN));
                s16x8 w;
#pragma unroll
                for (int j = 0; j < 8; ++j) w[j] = f2bf(src[j]);
                wreg[ks * 4 + gt] = w;
            }
        }
    }

    const int eb = tid >> 4;
    const int eu = tid & 15;
    const int unit_g = wgk * UPW + eu;
    float bias[4];
#pragma unroll
    for (int gt = 0; gt < 4; ++gt)
        bias[gt] = bih[gt * HH + unit_g] + bhh[gt * HH + unit_g];
    float c = 0.f;

    const int sb = tid >> 4;   // batch row this thread stages
    const int sk = tid & 15;   // group column

    float* gbuf = (float*)(smem + 65536);  // disjoint from A region

    const u64* ownbase = (LAYER == 0) ? &g_h0t[0][0][0] : &g_h1t[0][0][0];

    for (int t = 0; t < TT; ++t) {
        // ---- [A] speculative issue: own h[t] (+ cross h0[t+1] for L1) -----
        u64 ow[16];
        const u64* op = ownbase + (size_t)t * (BB * HH / 2) + (size_t)sb * (HH / 2);
#pragma unroll
        for (int g = 0; g < 4; ++g)
#pragma unroll
            for (int j = 0; j < 4; ++j)
                ow[g * 4 + j] = ald(op + (sk + 16 * g) * 4 + j);
        u64 cw[16];
        const u64* cp = &g_h0t[t + 1][sb][0];
        if constexpr (LAYER == 1) {
#pragma unroll
            for (int g = 0; g < 4; ++g)
#pragma unroll
                for (int j = 0; j < 4; ++j)
                    cw[g * 4 + j] = ald(cp + (sk + 16 * g) * 4 + j);
        }
        SCHED_FENCE();

        // ---- [B] all-wave flag poll (bandwidth gate; 4-8 ints per lane) ---
        {
            int rounds = 0;
            for (;;) {
                bool ok = true;
#pragma unroll
                for (int j = 0; j < 4; ++j) {
                    const int fi = lane * 4 + j;
                    if (LAYER == 0) {
                        ok &= (aldi(&g_wf0[fi]) >= t);
                    } else {
                        ok &= (aldi(&g_wf1[fi]) >= t);
                        ok &= (aldi(&g_wf0[fi]) >= t + 1);
                    }
                }
                if (__all(ok)) break;
                if (++rounds > (1 << 20)) break;  // hang escape
                if (rounds > 16) __builtin_amdgcn_s_sleep(1);
            }
        }

        // ---- [C] L0: stage x (read-only, plain cached loads) --------------
        if constexpr (LAYER == 0) {
#pragma unroll
            for (int g = 0; g < 2; ++g) {
                const int kg = sk + 16 * g;
                s16x8 v = *(const s16x8*)&g_xb[sb][t][kg * 8];
                *(s16x8*)(smem + sb * ROWB + ((kg * 16) ^ ((sb & 7) << 4))) = v;
            }
        }

        // ---- [D] own tag-check + masked retry, then stage -----------------
        {
            const u32 tago = (u32)t;
            int rounds = 0;
            for (;;) {
                u32 bad = 0;
#pragma unroll
                for (int w = 0; w < 16; ++w)
                    if ((u32)(ow[w] >> 32) != tago) bad |= (1u << w);
                if (!bad) break;
                if (++rounds > (1 << 17)) break;  // wrong answer beats hang
                if (rounds > 8) __builtin_amdgcn_s_sleep(1);
#pragma unroll
                for (int w = 0; w < 16; ++w)
                    if (bad & (1u << w))
                        ow[w] = ald(op + (sk + 16 * (w >> 2)) * 4 + (w & 3));
            }
#pragma unroll
            for (int g = 0; g < 4; ++g) {
                const int kg = sk + 16 * (g + (LAYER == 0 ? 2 : 4));
                s16x8 v;
#pragma unroll
                for (int j = 0; j < 4; ++j) {
                    v[2 * j]     = (short)(u32)ow[g * 4 + j];
                    v[2 * j + 1] = (short)((u32)ow[g * 4 + j] >> 16);
                }
                *(s16x8*)(smem + sb * ROWB + ((kg * 16) ^ ((sb & 7) << 4))) = v;
            }
        }

        // ---- [E] L1: cross tag-check + masked retry, then stage -----------
        if constexpr (LAYER == 1) {
            const u32 tagc = (u32)(t + 1);
            int rounds = 0;
            for (;;) {
                u32 bad = 0;
#pragma unroll
                for (int w = 0; w < 16; ++w)
                    if ((u32)(cw[w] >> 32) != tagc) bad |= (1u << w);
                if (!bad) break;
                if (++rounds > (1 << 17)) break;
                if (rounds > 8) __builtin_amdgcn_s_sleep(1);
#pragma unroll
                for (int w = 0; w < 16; ++w)
                    if (bad & (1u << w))
                        cw[w] = ald(cp + (sk + 16 * (w >> 2)) * 4 + (w & 3));
            }
#pragma unroll
            for (int g = 0; g < 4; ++g) {
                const int kg = sk + 16 * g;
                s16x8 v;
#pragma unroll
                for (int j = 0; j < 4; ++j) {
                    v[2 * j]     = (short)(u32)cw[g * 4 + j];
                    v[2 * j + 1] = (short)((u32)cw[g * 4 + j] >> 16);
                }
                *(s16x8*)(smem + sb * ROWB + ((kg * 16) ^ ((sb & 7) << 4))) = v;
            }
        }

        __syncthreads();  // b2: A tile complete

        // ---- MFMA ----------------------------------------------------------
        f32x4 acc[4] = {{0,0,0,0},{0,0,0,0},{0,0,0,0},{0,0,0,0}};
        {
            const int arow = m * 16 + u16i;
            const char* abase = smem + arow * ROWB;
            const int aswz = (arow & 7) << 4;
#pragma unroll
            for (int ks = 0; ks < NKQ; ++ks) {
                const int off = (q * QK + ks * 32 + hi * 8) * 2;
                s16x8 a = *(const s16x8*)(abase + (off ^ aswz));
#pragma unroll
                for (int gt = 0; gt < 4; ++gt)
                    acc[gt] = __builtin_amdgcn_mfma_f32_16x16x32_bf16(a, wreg[ks * 4 + gt], acc[gt], 0, 0, 0);
            }
        }

        // ---- partials -> gbuf (disjoint region) ----------------------------
#pragma unroll
        for (int gt = 0; gt < 4; ++gt) {
#pragma unroll
            for (int r = 0; r < 4; ++r) {
                const int b = m * 16 + hi * 4 + r;  // C row = (lane>>4)*4 + reg
                gbuf[(q * BB + b) * 68 + gt * 16 + u16i] = acc[gt][r];
            }
        }

        __syncthreads();  // b3: partials complete

        // ---- gates, state, tagged publish + per-wave flag ------------------
        {
            float gv[4];
#pragma unroll
            for (int gt = 0; gt < 4; ++gt) {
                float s = bias[gt];
#pragma unroll
                for (int qq = 0; qq < 4; ++qq) s += gbuf[(qq * BB + eb) * 68 + gt * 16 + eu];
                gv[gt] = s;
            }
            const float ig = sigm(gv[0]);
            const float fg = sigm(gv[1]);
            const float gg = tanh_f(gv[2]);
            const float og = sigm(gv[3]);
            c = fg * c + ig * gg;
            const float h = og * tanh_f(c);
            const u32 hu = (u32)(unsigned short)f2bf(h);
            const u32 other = __shfl_xor(hu, 1);
            if (LAYER == 1 && t == TT - 1) g_h1f[eb][unit_g] = h;
            if ((eu & 1) == 0) {
                const u64 wv = (u64)(hu | (other << 16)) | ((u64)(u32)(t + 1) << 32);
                u64* dst = (u64*)ownbase + (size_t)(t + 1) * (BB * HH / 2)
                         + (size_t)eb * (HH / 2) + unit_g / 2;
                __hip_atomic_store(dst, wv, __ATOMIC_RELAXED, __HIP_MEMORY_SCOPE_AGENT);
            }
            // per-wave flag: all lanes of this wave have ISSUED their stores
            // (same instruction stream); arrival order at MALL is covered by tags.
            if (lane == 0) {
                int* f = (LAYER == 0) ? &g_wf0[wgk * 8 + wave] : &g_wf1[wgk * 8 + wave];
                __hip_atomic_store(f, t + 1, __ATOMIC_RELAXED, __HIP_MEMORY_SCOPE_AGENT);
            }
            SCHED_FENCE();
        }
    }
}

__global__ __launch_bounds__(512, 1) void lstm_scan(
    const float* __restrict__ Wih0, const float* __restrict__ Whh0,
    const float* __restrict__ bih0, const float* __restrict__ bhh0,
    const float* __restrict__ Wih1, const float* __restrict__ Whh1,
    const float* __restrict__ bih1, const float* __restrict__ bhh1) {
    __shared__ __attribute__((aligned(16))) char smem[65536 + 4 * BB * 68 * 4];
    const int layer = blockIdx.x >> 5;
    const int wgk   = blockIdx.x & (NWG - 1);
    if (layer == 0) scan_layer<0>(smem, wgk, Wih0, Whh0, bih0, bhh0);
    else            scan_layer<1>(smem, wgk, Wih1, Whh1, bih1, bhh1);
}

// prep: zero flags; zero BOTH tagged h arrays (stale tags from a previous
// call are valid-looking -> must be cleared; slot-0 zero == {h=0, tag=0}
// which self-validates for t=0); cast x -> bf16.
__global__ void prep_kernel(const float* __restrict__ x) {
    const int wg = blockIdx.x;
    const int tid = threadIdx.x;
    if (wg == 0) {
        if (tid < NWG * 8) { g_wf0[tid] = 0; g_wf1[tid] = 0; }
    }
    if (wg >= 2) {
        const size_t i = (size_t)(wg - 2) * 256 + tid;  // one 8-float group
        const float4* xs = (const float4*)x + i * 2;
        const float4 a = xs[0], b = xs[1];
        s16x8 v;
        v[0] = f2bf(a.x); v[1] = f2bf(a.y); v[2] = f2bf(a.z); v[3] = f2bf(a.w);
        v[4] = f2bf(b.x); v[5] = f2bf(b.y); v[6] = f2bf(b.z); v[7] = f2bf(b.w);
        ((s16x8*)&g_xb[0][0][0])[i] = v;
        ulonglong2* p0 = (ulonglong2*)&g_h0t[0][0][0];
        ulonglong2* p1 = (ulonglong2*)&g_h1t[0][0][0];
        const size_t n = (size_t)(TT + 1) * BB * (HH / 2) / 2;  // 16B units
        const ulonglong2 z = {0ull, 0ull};
        for (size_t k = i; k < n; k += (size_t)8192 * 256) { p0[k] = z; p1[k] = z; }
    }
}

__global__ void out_kernel(const float* __restrict__ Wout, const float* __restrict__ bout,
                           float* __restrict__ out) {
    const int b = blockIdx.x;
    const int o = threadIdx.x;
    const float4* h4 = (const float4*)&g_h1f[b][0];
    const float4* w4 = (const float4*)(Wout + (size_t)o * HH);
    float s = bout[o];
    for (int k = 0; k < HH / 4; ++k) {
        const float4 a = h4[k], w = w4[k];
        s += a.x * w.x + a.y * w.y + a.z * w.z + a.w * w.w;
    }
    out[b * 256 + o] = s;
}

extern "C" void kernel_launch(void* const* d_in, const int* in_sizes, int n_in,
                              void* d_out, int out_size, void* d_ws, size_t ws_size,
                              hipStream_t stream) {
    const float* x    = (const float*)d_in[0];
    const float* Wih0 = (const float*)d_in[1];
    const float* Whh0 = (const float*)d_in[2];
    const float* bih0 = (const float*)d_in[3];
    const float* bhh0 = (const float*)d_in[4];
    const float* Wih1 = (const float*)d_in[5];
    const float* Whh1 = (const float*)d_in[6];
    const float* bih1 = (const float*)d_in[7];
    const float* bhh1 = (const float*)d_in[8];
    const float* Wout = (const float*)d_in[9];
    const float* bout = (const float*)d_in[10];
    float* out = (float*)d_out;

    hipLaunchKernelGGL(prep_kernel, dim3(2 + 8192), dim3(256), 0, stream, x);
    hipLaunchKernelGGL(lstm_scan, dim3(2 * NWG), dim3(512), 0, stream,
                       Wih0, Whh0, bih0, bhh0, Wih1, Whh1, bih1, bhh1);
    hipLaunchKernelGGL(out_kernel, dim3(BB), dim3(256), 0, stream, Wout, bout, out);
}

// Round 7
// 15858.730 us; speedup vs baseline: 6.3908x; 1.3344x over previous
//
#include <hip/hip_runtime.h>
#include <hip/hip_bf16.h>

#define TT 2048
#define BB 32
#define DD 256
#define HH 512
#define NWG 32      // workgroups per layer
#define UPW 16      // hidden units per workgroup
#define RING 64     // ring depth (power of 2); lag throttled to < 48

typedef unsigned long long u64;
typedef unsigned u32;
using f32x4 = __attribute__((ext_vector_type(4))) float;
using s16x8 = __attribute__((ext_vector_type(8))) short;

// Tagged h rings: u64 word = [h_even | h_odd<<16 | tag<<32], tag = t.
// 4 MB per layer -> L3/MALL-resident (the r6 mistake was 268 MB of tagged
// arrays thrashing past the 256 MB L3 to HBM). Relaxed agent atomics only.
// NO flags: consumers poll exactly the words they consume; a valid tag
// self-validates the data under any cache/ordering behavior.
__device__ __attribute__((aligned(16))) u64 g_r0[RING][BB][HH / 2];   // 4 MB
__device__ __attribute__((aligned(16))) u64 g_r1[RING][BB][HH / 2];   // 4 MB
__device__ __attribute__((aligned(16))) __hip_bfloat16 g_xb[BB][TT][DD];  // 32 MB
__device__ __attribute__((aligned(16))) float g_h1f[BB][HH];
__device__ int g_prog1;  // L1 progress (throttles L0 lag < RING)

#define RSLOT (BB * (HH / 2))   // u64 words per ring slot (8192)

__device__ __forceinline__ short f2bf(float f) {
    union { float f; unsigned u; } v; v.f = f;
    unsigned r = v.u + 0x7fffu + ((v.u >> 16) & 1u);  // RNE
    return (short)(r >> 16);
}
__device__ __forceinline__ float sigm(float x) { return 1.f / (1.f + __expf(-x)); }
__device__ __forceinline__ float tanh_f(float x) { return 1.f - 2.f / (__expf(2.f * x) + 1.f); }

__device__ __forceinline__ u64 ald(const u64* p) {
    return __hip_atomic_load(p, __ATOMIC_RELAXED, __HIP_MEMORY_SCOPE_AGENT);
}
__device__ __forceinline__ int aldi(const int* p) {
    return __hip_atomic_load(p, __ATOMIC_RELAXED, __HIP_MEMORY_SCOPE_AGENT);
}

// ---------------------------------------------------------------------------
// Persistent per-layer scan. wave = (m-tile, K-quarter); weights in VGPRs.
// Step: issue all tagged loads -> masked tag-retry -> LDS -> b2 -> MFMA ->
//       gbuf -> b3 -> gates -> tagged publish (fire-and-forget).
// ---------------------------------------------------------------------------
template <int LAYER>
__device__ void scan_layer(char* smem, int wgk,
                           const float* __restrict__ Wih, const float* __restrict__ Whh,
                           const float* __restrict__ bih, const float* __restrict__ bhh) {
    constexpr int KIN = (LAYER == 0) ? DD : HH;  // 256 / 512
    constexpr int KL  = KIN + HH;                // 768 / 1024
    constexpr int QK  = KL / 4;
    constexpr int NKQ = QK / 32;
    constexpr int ROWB = 2048;                   // LDS A row stride (bytes)

    const int tid  = threadIdx.x;
    const int wave = tid >> 6;
    const int lane = tid & 63;
    const int m    = wave & 1;
    const int q    = wave >> 1;
    const int u16i = lane & 15;
    const int hi   = lane >> 4;

    // ---- weights into registers (one-time) --------------------------------
    s16x8 wreg[NKQ * 4];
    {
        const int unit = wgk * UPW + u16i;
#pragma unroll
        for (int ks = 0; ks < NKQ; ++ks) {
#pragma unroll
            for (int gt = 0; gt < 4; ++gt) {
                const int k = q * QK + ks * 32 + hi * 8;
                const float* src = (k < KIN)
                    ? (Wih + (size_t)(gt * HH + unit) * KIN + k)
                    : (Whh + (size_t)(gt * HH + unit) * HH + (k - KIN));
                s16x8 w;
#pragma unroll
                for (int j = 0; j < 8; ++j) w[j] = f2bf(src[j]);
                wreg[ks * 4 + gt] = w;
            }
        }
    }

    const int eb = tid >> 4;
    const int eu = tid & 15;
    const int unit_g = wgk * UPW + eu;
    float bias[4];
#pragma unroll
    for (int gt = 0; gt < 4; ++gt)
        bias[gt] = bih[gt * HH + unit_g] + bhh[gt * HH + unit_g];
    float c = 0.f;

    const int sb = tid >> 4;   // batch row this thread stages
    const int sk = tid & 15;   // group column

    float* gbuf = (float*)(smem + 65536);  // disjoint from A region

    const u64* ownring = (LAYER == 0) ? &g_r0[0][0][0] : &g_r1[0][0][0];

    for (int t = 0; t < TT; ++t) {
        // ---- [T] L0 ring-overwrite throttle (off critical path) -----------
        if (LAYER == 0 && (t & 15) == 0 && t >= 32) {
            int it = 0;
            while (aldi(&g_prog1) < t - 40) {
                if (++it > (1 << 18)) break;
                __builtin_amdgcn_s_sleep(4);
            }
        }

        // ---- [A] issue ALL tagged loads (own + cross), 1 RT in flight -----
        u64 ow[16];
        const u64* op = ownring + (size_t)(t & (RING - 1)) * RSLOT + (size_t)sb * (HH / 2);
#pragma unroll
        for (int g = 0; g < 4; ++g)
#pragma unroll
            for (int j = 0; j < 4; ++j)
                ow[g * 4 + j] = ald(op + (sk + 16 * g) * 4 + j);

        u64 cw[16];
        const u64* cp = &g_r0[(t + 1) & (RING - 1)][sb][0];
        if constexpr (LAYER == 1) {
#pragma unroll
            for (int g = 0; g < 4; ++g)
#pragma unroll
                for (int j = 0; j < 4; ++j)
                    cw[g * 4 + j] = ald(cp + (sk + 16 * g) * 4 + j);
        }

        // ---- [C] L0: stage x (plain cached loads, independent) ------------
        if constexpr (LAYER == 0) {
#pragma unroll
            for (int g = 0; g < 2; ++g) {
                const int kg = sk + 16 * g;
                s16x8 v = *(const s16x8*)&g_xb[sb][t][kg * 8];
                *(s16x8*)(smem + sb * ROWB + ((kg * 16) ^ ((sb & 7) << 4))) = v;
            }
        }

        // ---- [D] own tag-check + masked retry, then stage -----------------
        {
            const u32 tago = (u32)t;
            int rounds = 0;
            for (;;) {
                u32 bad = 0;
#pragma unroll
                for (int w = 0; w < 16; ++w)
                    if ((u32)(ow[w] >> 32) != tago) bad |= (1u << w);
                if (!bad) break;
                if (++rounds > (1 << 17)) break;  // wrong answer beats hang
                if (rounds > 2) __builtin_amdgcn_s_sleep(1);
#pragma unroll
                for (int w = 0; w < 16; ++w)
                    if (bad & (1u << w))
                        ow[w] = ald(op + (sk + 16 * (w >> 2)) * 4 + (w & 3));
            }
#pragma unroll
            for (int g = 0; g < 4; ++g) {
                const int kg = sk + 16 * (g + (LAYER == 0 ? 2 : 4));
                s16x8 v;
#pragma unroll
                for (int j = 0; j < 4; ++j) {
                    v[2 * j]     = (short)(u32)ow[g * 4 + j];
                    v[2 * j + 1] = (short)((u32)ow[g * 4 + j] >> 16);
                }
                *(s16x8*)(smem + sb * ROWB + ((kg * 16) ^ ((sb & 7) << 4))) = v;
            }
        }

        // ---- [E] L1: cross tag-check + masked retry, then stage -----------
        if constexpr (LAYER == 1) {
            const u32 tagc = (u32)(t + 1);
            int rounds = 0;
            for (;;) {
                u32 bad = 0;
#pragma unroll
                for (int w = 0; w < 16; ++w)
                    if ((u32)(cw[w] >> 32) != tagc) bad |= (1u << w);
                if (!bad) break;
                if (++rounds > (1 << 17)) break;
                if (rounds > 2) __builtin_amdgcn_s_sleep(1);
#pragma unroll
                for (int w = 0; w < 16; ++w)
                    if (bad & (1u << w))
                        cw[w] = ald(cp + (sk + 16 * (w >> 2)) * 4 + (w & 3));
            }
#pragma unroll
            for (int g = 0; g < 4; ++g) {
                const int kg = sk + 16 * g;
                s16x8 v;
#pragma unroll
                for (int j = 0; j < 4; ++j) {
                    v[2 * j]     = (short)(u32)cw[g * 4 + j];
                    v[2 * j + 1] = (short)((u32)cw[g * 4 + j] >> 16);
                }
                *(s16x8*)(smem + sb * ROWB + ((kg * 16) ^ ((sb & 7) << 4))) = v;
            }
        }

        __syncthreads();  // b2: A tile complete

        // ---- MFMA ----------------------------------------------------------
        f32x4 acc[4] = {{0,0,0,0},{0,0,0,0},{0,0,0,0},{0,0,0,0}};
        {
            const int arow = m * 16 + u16i;
            const char* abase = smem + arow * ROWB;
            const int aswz = (arow & 7) << 4;
#pragma unroll
            for (int ks = 0; ks < NKQ; ++ks) {
                const int off = (q * QK + ks * 32 + hi * 8) * 2;
                s16x8 a = *(const s16x8*)(abase + (off ^ aswz));
#pragma unroll
                for (int gt = 0; gt < 4; ++gt)
                    acc[gt] = __builtin_amdgcn_mfma_f32_16x16x32_bf16(a, wreg[ks * 4 + gt], acc[gt], 0, 0, 0);
            }
        }

        // ---- partials -> gbuf (disjoint region) ----------------------------
#pragma unroll
        for (int gt = 0; gt < 4; ++gt) {
#pragma unroll
            for (int r = 0; r < 4; ++r) {
                const int b = m * 16 + hi * 4 + r;  // C row = (lane>>4)*4 + reg
                gbuf[(q * BB + b) * 68 + gt * 16 + u16i] = acc[gt][r];
            }
        }

        __syncthreads();  // b3: partials complete

        // ---- gates, state, tagged publish (fire-and-forget) ----------------
        {
            float gv[4];
#pragma unroll
            for (int gt = 0; gt < 4; ++gt) {
                float s = bias[gt];
#pragma unroll
                for (int qq = 0; qq < 4; ++qq) s += gbuf[(qq * BB + eb) * 68 + gt * 16 + eu];
                gv[gt] = s;
            }
            const float ig = sigm(gv[0]);
            const float fg = sigm(gv[1]);
            const float gg = tanh_f(gv[2]);
            const float og = sigm(gv[3]);
            c = fg * c + ig * gg;
            const float h = og * tanh_f(c);
            const u32 hu = (u32)(unsigned short)f2bf(h);
            const u32 other = __shfl_xor(hu, 1);
            if (LAYER == 1 && t == TT - 1) g_h1f[eb][unit_g] = h;
            if ((eu & 1) == 0) {
                const u64 wv = (u64)(hu | (other << 16)) | ((u64)(u32)(t + 1) << 32);
                u64* dst = (u64*)ownring + (size_t)((t + 1) & (RING - 1)) * RSLOT
                         + (size_t)eb * (HH / 2) + unit_g / 2;
                __hip_atomic_store(dst, wv, __ATOMIC_RELAXED, __HIP_MEMORY_SCOPE_AGENT);
            }
            if (LAYER == 1 && wgk == 0 && tid == 0)
                __hip_atomic_store(&g_prog1, t + 1, __ATOMIC_RELAXED, __HIP_MEMORY_SCOPE_AGENT);
        }
    }
}

__global__ __launch_bounds__(512) void lstm_scan(
    const float* __restrict__ Wih0, const float* __restrict__ Whh0,
    const float* __restrict__ bih0, const float* __restrict__ bhh0,
    const float* __restrict__ Wih1, const float* __restrict__ Whh1,
    const float* __restrict__ bih1, const float* __restrict__ bhh1) {
    __shared__ __attribute__((aligned(16))) char smem[65536 + 4 * BB * 68 * 4];
    const int layer = blockIdx.x >> 5;
    const int wgk   = blockIdx.x & (NWG - 1);
    if (layer == 0) scan_layer<0>(smem, wgk, Wih0, Whh0, bih0, bhh0);
    else            scan_layer<1>(smem, wgk, Wih1, Whh1, bih1, bhh1);
}

// prep: zero rings + progress (stale tags from a previous replay can alias
// at the final wrap -> must clear); cast x -> bf16. Kernel-end release makes
// these plain stores visible to the scan's agent-scope atomics.
__global__ void prep_kernel(const float* __restrict__ x) {
    const int wg = blockIdx.x;
    const int tid = threadIdx.x;
    if (wg == 0 && tid == 0) g_prog1 = 0;
    if (wg >= 2) {
        const size_t i = (size_t)(wg - 2) * 256 + tid;  // one 8-float group
        const float4* xs = (const float4*)x + i * 2;
        const float4 a = xs[0], b = xs[1];
        s16x8 v;
        v[0] = f2bf(a.x); v[1] = f2bf(a.y); v[2] = f2bf(a.z); v[3] = f2bf(a.w);
        v[4] = f2bf(b.x); v[5] = f2bf(b.y); v[6] = f2bf(b.z); v[7] = f2bf(b.w);
        ((s16x8*)&g_xb[0][0][0])[i] = v;
        // ring zero: 2 x 4 MB = 524288 ulonglong2 total, strided over 8192 wgs
        ulonglong2* p0 = (ulonglong2*)&g_r0[0][0][0];
        ulonglong2* p1 = (ulonglong2*)&g_r1[0][0][0];
        const size_t n = (size_t)RING * BB * (HH / 2) / 2;  // 262144 x 16B
        const ulonglong2 z = {0ull, 0ull};
        for (size_t k = i; k < n; k += (size_t)8192 * 256) { p0[k] = z; p1[k] = z; }
    }
}

__global__ void out_kernel(const float* __restrict__ Wout, const float* __restrict__ bout,
                           float* __restrict__ out) {
    const int b = blockIdx.x;
    const int o = threadIdx.x;
    const float4* h4 = (const float4*)&g_h1f[b][0];
    const float4* w4 = (const float4*)(Wout + (size_t)o * HH);
    float s = bout[o];
    for (int k = 0; k < HH / 4; ++k) {
        const float4 a = h4[k], w = w4[k];
        s += a.x * w.x + a.y * w.y + a.z * w.z + a.w * w.w;
    }
    out[b * 256 + o] = s;
}

extern "C" void kernel_launch(void* const* d_in, const int* in_sizes, int n_in,
                              void* d_out, int out_size, void* d_ws, size_t ws_size,
                              hipStream_t stream) {
    const float* x    = (const float*)d_in[0];
    const float* Wih0 = (const float*)d_in[1];
    const float* Whh0 = (const float*)d_in[2];
    const float* bih0 = (const float*)d_in[3];
    const float* bhh0 = (const float*)d_in[4];
    const float* Wih1 = (const float*)d_in[5];
    const float* Whh1 = (const float*)d_in[6];
    const float* bih1 = (const float*)d_in[7];
    const float* bhh1 = (const float*)d_in[8];
    const float* Wout = (const float*)d_in[9];
    const float* bout = (const float*)d_in[10];
    float* out = (float*)d_out;

    hipLaunchKernelGGL(prep_kernel, dim3(2 + 8192), dim3(256), 0, stream, x);
    hipLaunchKernelGGL(lstm_scan, dim3(2 * NWG), dim3(512), 0, stream,
                       Wih0, Whh0, bih0, bhh0, Wih1, Whh1, bih1, bhh1);
    hipLaunchKernelGGL(out_kernel, dim3(BB), dim3(256), 0, stream, Wout, bout, out);
}

// Round 8
// 14029.060 us; speedup vs baseline: 7.2242x; 1.1304x over previous
//
#include <hip/hip_runtime.h>
#include <hip/hip_bf16.h>

#define TT 2048
#define BB 32
#define DD 256
#define HH 512
#define NWG 32      // workgroups per layer
#define UPW 16      // hidden units per workgroup
#define RING 64     // ring depth (power of 2); L0 lag throttled to < 48

typedef unsigned long long u64;
typedef unsigned u32;
using f32x4 = __attribute__((ext_vector_type(4))) float;
using s16x8 = __attribute__((ext_vector_type(8))) short;

// Tagged h rings (L3-resident, 4 MB/layer): u64 = [h_even|h_odd<<16|t<<32].
// Flags: per-wg monotonic step counters — gate the bulk loads so data moves
// ~once (r7 lesson: ungated polling congests MALL). Tags remain the
// correctness authority (no producer drain, no fences, benign races).
__device__ __attribute__((aligned(16))) u64 g_r0[RING][BB][HH / 2];   // 4 MB
__device__ __attribute__((aligned(16))) u64 g_r1[RING][BB][HH / 2];   // 4 MB
__device__ __attribute__((aligned(16))) __hip_bfloat16 g_xb[BB][TT][DD];  // 32 MB
__device__ __attribute__((aligned(16))) float g_h1f[BB][HH];
__device__ int g_f0[NWG];   // per-wg monotonic flags, layer 0 (one 128B line)
__device__ int g_f1[NWG];   // layer 1
__device__ int g_prog1;     // L1 progress (throttles L0 lag < RING)

#define RSLOT (BB * (HH / 2))   // u64 words per ring slot (8192)
#define GBS 72                  // gbuf row stride in floats (bank-conflict-free)

__device__ __forceinline__ short f2bf(float f) {
    union { float f; unsigned u; } v; v.f = f;
    unsigned r = v.u + 0x7fffu + ((v.u >> 16) & 1u);  // RNE
    return (short)(r >> 16);
}
__device__ __forceinline__ float sigm(float x) { return 1.f / (1.f + __expf(-x)); }
__device__ __forceinline__ float tanh_f(float x) { return 1.f - 2.f / (__expf(2.f * x) + 1.f); }

__device__ __forceinline__ u64 ald(const u64* p) {
    return __hip_atomic_load(p, __ATOMIC_RELAXED, __HIP_MEMORY_SCOPE_AGENT);
}
__device__ __forceinline__ int aldi(const int* p) {
    return __hip_atomic_load(p, __ATOMIC_RELAXED, __HIP_MEMORY_SCOPE_AGENT);
}

// ---------------------------------------------------------------------------
// Step: [L1: issue cross loads] -> flag poll (1 load/lane/round) ->
//       issue own loads -> stage x / cross -> own tag-check + stage ->
//       b2 -> MFMA -> gbuf -> b3 -> ew -> tagged publish -> flag store.
// ---------------------------------------------------------------------------
template <int LAYER>
__device__ void scan_layer(char* smem, int wgk,
                           const float* __restrict__ Wih, const float* __restrict__ Whh,
                           const float* __restrict__ bih, const float* __restrict__ bhh) {
    constexpr int KIN = (LAYER == 0) ? DD : HH;  // 256 / 512
    constexpr int KL  = KIN + HH;                // 768 / 1024
    constexpr int QK  = KL / 4;
    constexpr int NKQ = QK / 32;
    constexpr int ROWB = 2048;                   // LDS A row stride (bytes)

    const int tid  = threadIdx.x;
    const int wave = tid >> 6;
    const int lane = tid & 63;
    const int m    = wave & 1;
    const int q    = wave >> 1;
    const int u16i = lane & 15;
    const int hi   = lane >> 4;

    // ---- weights into registers (one-time) --------------------------------
    s16x8 wreg[NKQ * 4];
    {
        const int unit = wgk * UPW + u16i;
#pragma unroll
        for (int ks = 0; ks < NKQ; ++ks) {
#pragma unroll
            for (int gt = 0; gt < 4; ++gt) {
                const int k = q * QK + ks * 32 + hi * 8;
                const float* src = (k < KIN)
                    ? (Wih + (size_t)(gt * HH + unit) * KIN + k)
                    : (Whh + (size_t)(gt * HH + unit) * HH + (k - KIN));
                s16x8 w;
#pragma unroll
                for (int j = 0; j < 8; ++j) w[j] = f2bf(src[j]);
                wreg[ks * 4 + gt] = w;
            }
        }
    }

    const int eb = tid >> 4;
    const int eu = tid & 15;
    const int unit_g = wgk * UPW + eu;
    float bias[4];
#pragma unroll
    for (int gt = 0; gt < 4; ++gt)
        bias[gt] = bih[gt * HH + unit_g] + bhh[gt * HH + unit_g];
    float c = 0.f;

    const int sb = tid >> 4;   // batch row this thread stages
    const int sk = tid & 15;   // group column

    float* gbuf = (float*)(smem + 65536);  // disjoint from A region

    const u64* ownring = (LAYER == 0) ? &g_r0[0][0][0] : &g_r1[0][0][0];
    const int fi = lane & (NWG - 1);

    for (int t = 0; t < TT; ++t) {
        // ---- [T] L0 ring-overwrite throttle (off critical path) -----------
        if (LAYER == 0 && (t & 15) == 0 && t >= 32) {
            int it = 0;
            while (aldi(&g_prog1) < t - 40) {
                if (++it > (1 << 18)) break;
                __builtin_amdgcn_s_sleep(4);
            }
        }

        // ---- [A] L1: speculative cross issue (L0 ~1 step ahead -> valid) --
        u64 cw[16];
        const u64* cp = &g_r0[(t + 1) & (RING - 1)][sb][0];
        if constexpr (LAYER == 1) {
#pragma unroll
            for (int g = 0; g < 4; ++g)
#pragma unroll
                for (int j = 0; j < 4; ++j)
                    cw[g * 4 + j] = ald(cp + (sk + 16 * g) * 4 + j);
        }

        // ---- [B] flag poll: 1 (L0) or 2 (L1) 4B atomic loads per lane -----
        {
            int rounds = 0;
            for (;;) {
                bool ok;
                if (LAYER == 0) {
                    ok = (aldi(&g_f0[fi]) >= t);
                } else {
                    ok = (aldi(&g_f1[fi]) >= t) & (aldi(&g_f0[fi]) >= t + 1);
                }
                if (__all(ok)) break;
                if (++rounds > (1 << 20)) break;  // hang escape
                if (rounds > 8) __builtin_amdgcn_s_sleep(1);
            }
        }

        // ---- [C] own data issue (gated: expect tags valid on arrival) -----
        u64 ow[16];
        const u64* op = ownring + (size_t)(t & (RING - 1)) * RSLOT + (size_t)sb * (HH / 2);
#pragma unroll
        for (int g = 0; g < 4; ++g)
#pragma unroll
            for (int j = 0; j < 4; ++j)
                ow[g * 4 + j] = ald(op + (sk + 16 * g) * 4 + j);

        // ---- [D] stage x (L0) / cross (L1) while own loads are in flight --
        if constexpr (LAYER == 0) {
#pragma unroll
            for (int g = 0; g < 2; ++g) {
                const int kg = sk + 16 * g;
                s16x8 v = *(const s16x8*)&g_xb[sb][t][kg * 8];
                *(s16x8*)(smem + sb * ROWB + ((kg * 16) ^ ((sb & 7) << 4))) = v;
            }
        } else {
            const u32 tagc = (u32)(t + 1);
            int rounds = 0;
            for (;;) {
                u32 bad = 0;
#pragma unroll
                for (int w = 0; w < 16; ++w)
                    if ((u32)(cw[w] >> 32) != tagc) bad |= (1u << w);
                if (!bad) break;
                if (++rounds > (1 << 17)) break;
                if (rounds > 2) __builtin_amdgcn_s_sleep(1);
#pragma unroll
                for (int w = 0; w < 16; ++w)
                    if (bad & (1u << w))
                        cw[w] = ald(cp + (sk + 16 * (w >> 2)) * 4 + (w & 3));
            }
#pragma unroll
            for (int g = 0; g < 4; ++g) {
                const int kg = sk + 16 * g;
                s16x8 v;
#pragma unroll
                for (int j = 0; j < 4; ++j) {
                    v[2 * j]     = (short)(u32)cw[g * 4 + j];
                    v[2 * j + 1] = (short)((u32)cw[g * 4 + j] >> 16);
                }
                *(s16x8*)(smem + sb * ROWB + ((kg * 16) ^ ((sb & 7) << 4))) = v;
            }
        }

        // ---- [E] own tag-check (usually clean) + masked retry, stage ------
        {
            const u32 tago = (u32)t;
            int rounds = 0;
            for (;;) {
                u32 bad = 0;
#pragma unroll
                for (int w = 0; w < 16; ++w)
                    if ((u32)(ow[w] >> 32) != tago) bad |= (1u << w);
                if (!bad) break;
                if (++rounds > (1 << 17)) break;  // wrong answer beats hang
                if (rounds > 2) __builtin_amdgcn_s_sleep(1);
#pragma unroll
                for (int w = 0; w < 16; ++w)
                    if (bad & (1u << w))
                        ow[w] = ald(op + (sk + 16 * (w >> 2)) * 4 + (w & 3));
            }
#pragma unroll
            for (int g = 0; g < 4; ++g) {
                const int kg = sk + 16 * (g + (LAYER == 0 ? 2 : 4));
                s16x8 v;
#pragma unroll
                for (int j = 0; j < 4; ++j) {
                    v[2 * j]     = (short)(u32)ow[g * 4 + j];
                    v[2 * j + 1] = (short)((u32)ow[g * 4 + j] >> 16);
                }
                *(s16x8*)(smem + sb * ROWB + ((kg * 16) ^ ((sb & 7) << 4))) = v;
            }
        }

        __syncthreads();  // b2: A tile complete

        // ---- MFMA ----------------------------------------------------------
        f32x4 acc[4] = {{0,0,0,0},{0,0,0,0},{0,0,0,0},{0,0,0,0}};
        {
            const int arow = m * 16 + u16i;
            const char* abase = smem + arow * ROWB;
            const int aswz = (arow & 7) << 4;
#pragma unroll
            for (int ks = 0; ks < NKQ; ++ks) {
                const int off = (q * QK + ks * 32 + hi * 8) * 2;
                s16x8 a = *(const s16x8*)(abase + (off ^ aswz));
#pragma unroll
                for (int gt = 0; gt < 4; ++gt)
                    acc[gt] = __builtin_amdgcn_mfma_f32_16x16x32_bf16(a, wreg[ks * 4 + gt], acc[gt], 0, 0, 0);
            }
        }

        // ---- partials -> gbuf (disjoint region) ----------------------------
#pragma unroll
        for (int gt = 0; gt < 4; ++gt) {
#pragma unroll
            for (int r = 0; r < 4; ++r) {
                const int b = m * 16 + hi * 4 + r;  // C row = (lane>>4)*4 + reg
                gbuf[(q * BB + b) * GBS + gt * 16 + u16i] = acc[gt][r];
            }
        }

        __syncthreads();  // b3: partials complete

        // ---- gates, state, tagged publish + per-wg flag --------------------
        {
            float gv[4];
#pragma unroll
            for (int gt = 0; gt < 4; ++gt) {
                float s = bias[gt];
#pragma unroll
                for (int qq = 0; qq < 4; ++qq) s += gbuf[(qq * BB + eb) * GBS + gt * 16 + eu];
                gv[gt] = s;
            }
            const float ig = sigm(gv[0]);
            const float fg = sigm(gv[1]);
            const float gg = tanh_f(gv[2]);
            const float og = sigm(gv[3]);
            c = fg * c + ig * gg;
            const float h = og * tanh_f(c);
            const u32 hu = (u32)(unsigned short)f2bf(h);
            const u32 other = __shfl_xor(hu, 1);
            if (LAYER == 1 && t == TT - 1) g_h1f[eb][unit_g] = h;
            if ((eu & 1) == 0) {
                const u64 wv = (u64)(hu | (other << 16)) | ((u64)(u32)(t + 1) << 32);
                u64* dst = (u64*)ownring + (size_t)((t + 1) & (RING - 1)) * RSLOT
                         + (size_t)eb * (HH / 2) + unit_g / 2;
                __hip_atomic_store(dst, wv, __ATOMIC_RELAXED, __HIP_MEMORY_SCOPE_AGENT);
            }
            // flag issued right after data stores; tags cover the race.
            if (tid == 0) {
                int* f = (LAYER == 0) ? &g_f0[wgk] : &g_f1[wgk];
                __hip_atomic_store(f, t + 1, __ATOMIC_RELAXED, __HIP_MEMORY_SCOPE_AGENT);
            }
            if (LAYER == 1 && wgk == 0 && tid == 0)
                __hip_atomic_store(&g_prog1, t + 1, __ATOMIC_RELAXED, __HIP_MEMORY_SCOPE_AGENT);
        }
    }
}

__global__ __launch_bounds__(512) void lstm_scan(
    const float* __restrict__ Wih0, const float* __restrict__ Whh0,
    const float* __restrict__ bih0, const float* __restrict__ bhh0,
    const float* __restrict__ Wih1, const float* __restrict__ Whh1,
    const float* __restrict__ bih1, const float* __restrict__ bhh1) {
    __shared__ __attribute__((aligned(16))) char smem[65536 + 4 * BB * GBS * 4];
    const int layer = blockIdx.x >> 5;
    const int wgk   = blockIdx.x & (NWG - 1);
    if (layer == 0) scan_layer<0>(smem, wgk, Wih0, Whh0, bih0, bhh0);
    else            scan_layer<1>(smem, wgk, Wih1, Whh1, bih1, bhh1);
}

// prep: zero rings (stale tags alias at wrap), flags, progress; cast x->bf16.
__global__ void prep_kernel(const float* __restrict__ x) {
    const int wg = blockIdx.x;
    const int tid = threadIdx.x;
    if (wg == 0) {
        if (tid == 0) g_prog1 = 0;
        if (tid < NWG) { g_f0[tid] = 0; g_f1[tid] = 0; }
    }
    if (wg >= 2) {
        const size_t i = (size_t)(wg - 2) * 256 + tid;  // one 8-float group
        const float4* xs = (const float4*)x + i * 2;
        const float4 a = xs[0], b = xs[1];
        s16x8 v;
        v[0] = f2bf(a.x); v[1] = f2bf(a.y); v[2] = f2bf(a.z); v[3] = f2bf(a.w);
        v[4] = f2bf(b.x); v[5] = f2bf(b.y); v[6] = f2bf(b.z); v[7] = f2bf(b.w);
        ((s16x8*)&g_xb[0][0][0])[i] = v;
        ulonglong2* p0 = (ulonglong2*)&g_r0[0][0][0];
        ulonglong2* p1 = (ulonglong2*)&g_r1[0][0][0];
        const size_t n = (size_t)RING * BB * (HH / 2) / 2;  // 262144 x 16B
        const ulonglong2 z = {0ull, 0ull};
        for (size_t k = i; k < n; k += (size_t)8192 * 256) { p0[k] = z; p1[k] = z; }
    }
}

__global__ void out_kernel(const float* __restrict__ Wout, const float* __restrict__ bout,
                           float* __restrict__ out) {
    const int b = blockIdx.x;
    const int o = threadIdx.x;
    const float4* h4 = (const float4*)&g_h1f[b][0];
    const float4* w4 = (const float4*)(Wout + (size_t)o * HH);
    float s = bout[o];
    for (int k = 0; k < HH / 4; ++k) {
        const float4 a = h4[k], w = w4[k];
        s += a.x * w.x + a.y * w.y + a.z * w.z + a.w * w.w;
    }
    out[b * 256 + o] = s;
}

extern "C" void kernel_launch(void* const* d_in, const int* in_sizes, int n_in,
                              void* d_out, int out_size, void* d_ws, size_t ws_size,
                              hipStream_t stream) {
    const float* x    = (const float*)d_in[0];
    const float* Wih0 = (const float*)d_in[1];
    const float* Whh0 = (const float*)d_in[2];
    const float* bih0 = (const float*)d_in[3];
    const float* bhh0 = (const float*)d_in[4];
    const float* Wih1 = (const float*)d_in[5];
    const float* Whh1 = (const float*)d_in[6];
    const float* bih1 = (const float*)d_in[7];
    const float* bhh1 = (const float*)d_in[8];
    const float* Wout = (const float*)d_in[9];
    const float* bout = (const float*)d_in[10];
    float* out = (float*)d_out;

    hipLaunchKernelGGL(prep_kernel, dim3(2 + 8192), dim3(256), 0, stream, x);
    hipLaunchKernelGGL(lstm_scan, dim3(2 * NWG), dim3(512), 0, stream,
                       Wih0, Whh0, bih0, bhh0, Wih1, Whh1, bih1, bhh1);
    hipLaunchKernelGGL(out_kernel, dim3(BB), dim3(256), 0, stream, Wout, bout, out);
}